// Round 1
// baseline (100.786 us; speedup 1.0000x reference)
//
#include <hip/hip_runtime.h>

// Bessel order-5 IIR filter, B=64 rows x T=131072 samples, f32.
// Strategy: linearity => skip xmax normalization. Poles |pz|<=0.60 =>
// 64-sample zero-state warmup makes chunks independent to < 1e-14 rel.
// One thread per 64-output chunk, fully parallel, single kernel.

constexpr int T_LEN   = 131072;
constexpr int B_ROWS  = 64;
constexpr int CHUNK   = 64;            // outputs per thread
constexpr int WARM    = 64;            // zero-state warmup samples
constexpr int CPR     = T_LEN / CHUNK; // chunks per row = 2048

__global__ __launch_bounds__(256) void bessel_iir_kernel(
    const float* __restrict__ x,
    const float* __restrict__ bco,
    const float* __restrict__ aco,
    float* __restrict__ y)
{
    const int tid = blockIdx.x * blockDim.x + threadIdx.x;
    const int row = tid / CPR;
    const int c   = tid % CPR;

    const float* __restrict__ xr = x + (size_t)row * T_LEN;
    float* __restrict__       yr = y + (size_t)row * T_LEN;

    // normalized coefficients (a0 == 1 for this filter, but follow the ref)
    const float inv = 1.0f / aco[0];
    const float b0 = bco[0] * inv, b1 = bco[1] * inv, b2 = bco[2] * inv,
                b3 = bco[3] * inv, b4 = bco[4] * inv, b5 = bco[5] * inv;
    const float a1 = aco[1] * inv, a2 = aco[2] * inv, a3 = aco[3] * inv,
                a4 = aco[4] * inv, a5 = aco[5] * inv;

    const int t0 = c * CHUNK;   // first output sample of this chunk
    const int ts = t0 - WARM;   // warmup start (>=0 for c>=1)

    // IIR state: y_{t-1}..y_{t-5}; FIR window: x_{t-1}..x_{t-5}
    float y1 = 0.f, y2 = 0.f, y3 = 0.f, y4 = 0.f, y5 = 0.f;
    float xm1 = 0.f, xm2 = 0.f, xm3 = 0.f, xm4 = 0.f, xm5 = 0.f;

    // 4-sample step: consumes xv = {x_t, x_{t+1}, x_{t+2}, x_{t+3}}
    auto step4 = [&](const float4 xv, float4& out) {
        float f0 = b0*xv.x + b1*xm1 + b2*xm2 + b3*xm3 + b4*xm4 + b5*xm5;
        float o0 = f0 - a1*y1 - a2*y2 - a3*y3 - a4*y4 - a5*y5;
        float f1 = b0*xv.y + b1*xv.x + b2*xm1 + b3*xm2 + b4*xm3 + b5*xm4;
        float o1 = f1 - a1*o0 - a2*y1 - a3*y2 - a4*y3 - a5*y4;
        float f2 = b0*xv.z + b1*xv.y + b2*xv.x + b3*xm1 + b4*xm2 + b5*xm3;
        float o2 = f2 - a1*o1 - a2*o0 - a3*y1 - a4*y2 - a5*y3;
        float f3 = b0*xv.w + b1*xv.z + b2*xv.y + b3*xv.x + b4*xm1 + b5*xm2;
        float o3 = f3 - a1*o2 - a2*o1 - a3*o0 - a4*y1 - a5*y2;
        // rotate state
        y5 = y1;  y4 = o0; y3 = o1; y2 = o2; y1 = o3;
        xm5 = xm1; xm4 = xv.x; xm3 = xv.y; xm2 = xv.z; xm1 = xv.w;
        out.x = o0; out.y = o1; out.z = o2; out.w = o3;
    };

    if (c > 0) {
        // prefill FIR window; for c==1, ts==0 so x_{-1..-5} stay 0
        if (ts >= 5) {
            xm1 = xr[ts-1]; xm2 = xr[ts-2]; xm3 = xr[ts-3];
            xm4 = xr[ts-4]; xm5 = xr[ts-5];
        }
        // warmup: run recurrence, discard outputs
        #pragma unroll 4
        for (int t = ts; t < t0; t += 4) {
            float4 xv = *(const float4*)(xr + t);
            float4 dump;
            step4(xv, dump);
        }
    }
    // (c==0: warmup region is all zeros -> state stays zero, skip it)

    // main: compute and store CHUNK outputs
    #pragma unroll 4
    for (int t = t0; t < t0 + CHUNK; t += 4) {
        float4 xv = *(const float4*)(xr + t);
        float4 ov;
        step4(xv, ov);
        *(float4*)(yr + t) = ov;
    }
}

extern "C" void kernel_launch(void* const* d_in, const int* in_sizes, int n_in,
                              void* d_out, int out_size, void* d_ws, size_t ws_size,
                              hipStream_t stream) {
    const float* x   = (const float*)d_in[0];
    const float* bco = (const float*)d_in[1];
    const float* aco = (const float*)d_in[2];
    float* y = (float*)d_out;

    const int total_threads = B_ROWS * CPR;   // 131072
    const int block = 256;
    const int grid  = total_threads / block;  // 512
    bessel_iir_kernel<<<grid, block, 0, stream>>>(x, bco, aco, y);
}

// Round 2
// 97.917 us; speedup vs baseline: 1.0293x; 1.0293x over previous
//
#include <hip/hip_runtime.h>

// Bessel order-5 IIR, B=64 x T=131072, f32.
// R1: LDS-tiled. Block = 256 threads = 8192-sample span of one row.
// Phase 1: coalesced float4 global->LDS (span + 96-sample head).
// Phase 2: per-thread warmup(64)+chunk(32) IIR from LDS (padded, conflict-free),
//          y into second LDS buffer.
// Phase 3: coalesced float4 LDS->global store.
// Warmup truncation: max |pole| ~ 0.60 -> 0.60^64 ~ 6e-15, below f32 eps.

constexpr int T_LEN  = 131072;
constexpr int B_ROWS = 64;
constexpr int CHUNK  = 32;             // outputs per thread
constexpr int WARM   = 64;             // zero-state warmup samples
constexpr int HEAD   = 96;             // staged samples before span (warm + history + align)
constexpr int BLOCK  = 256;
constexpr int SPAN   = BLOCK * CHUNK;  // 8192 samples per block
constexpr int BPR    = T_LEN / SPAN;   // 16 blocks per row
constexpr int XTOT   = HEAD + SPAN;    // 8288 staged x samples
constexpr int XPAD   = XTOT + XTOT / 32;  // 8547 (+1 float pad per 32)
constexpr int YPAD   = SPAN + SPAN / 32;  // 8448

__device__ __forceinline__ int padi(int s) { return s + (s >> 5); }

__global__ __launch_bounds__(BLOCK, 2) void bessel_tile_kernel(
    const float* __restrict__ x,
    const float* __restrict__ bco,
    const float* __restrict__ aco,
    float* __restrict__ y)
{
    __shared__ float xs[XPAD];
    __shared__ float ys[YPAD];

    const int b    = blockIdx.x;
    const int row  = b / BPR;
    const int tile = b % BPR;
    const int base = tile * SPAN;
    const int j    = threadIdx.x;

    const float* __restrict__ xr = x + (size_t)row * T_LEN;
    float* __restrict__       yr = y + (size_t)row * T_LEN;

    // ---- Phase 1: stage x[base-HEAD .. base+SPAN) into padded LDS ----
    if (tile == 0) {
        // head is x[-96..0) == zeros
        for (int s = j; s < HEAD; s += BLOCK)
            xs[padi(s)] = 0.0f;
        #pragma unroll
        for (int it = 0; it < SPAN / 4 / BLOCK; ++it) {   // 8 iters
            int k = j + it * BLOCK;
            float4 v = *(const float4*)(xr + base + 4 * k);
            int S = HEAD + 4 * k;
            int p = padi(S);                 // S%4==0 => S..S+3 same 32-group
            xs[p] = v.x; xs[p + 1] = v.y; xs[p + 2] = v.z; xs[p + 3] = v.w;
        }
    } else {
        for (int k = j; k < XTOT / 4; k += BLOCK) {       // 2072 float4, 9 iters
            float4 v = *(const float4*)(xr + base - HEAD + 4 * k);
            int S = 4 * k;
            int p = padi(S);
            xs[p] = v.x; xs[p + 1] = v.y; xs[p + 2] = v.z; xs[p + 3] = v.w;
        }
    }

    // normalized coefficients (uniform, cheap)
    const float inv = 1.0f / aco[0];
    const float b0 = bco[0] * inv, b1 = bco[1] * inv, b2 = bco[2] * inv,
                b3 = bco[3] * inv, b4 = bco[4] * inv, b5 = bco[5] * inv;
    const float a1 = aco[1] * inv, a2 = aco[2] * inv, a3 = aco[3] * inv,
                a4 = aco[4] * inv, a5 = aco[5] * inv;

    __syncthreads();

    // ---- Phase 2: per-thread IIR ----
    // thread j owns output samples S0..S0+CHUNK (LDS-relative), S0 = HEAD + j*CHUNK
    {
        const int S0 = HEAD + j * CHUNK;
        const int ws = S0 - WARM;          // >= 32 always
        float y1 = 0.f, y2 = 0.f, y3 = 0.f, y4 = 0.f, y5 = 0.f;
        float xm1 = xs[padi(ws - 1)], xm2 = xs[padi(ws - 2)], xm3 = xs[padi(ws - 3)],
              xm4 = xs[padi(ws - 4)], xm5 = xs[padi(ws - 5)];

        #pragma unroll 8
        for (int t = ws; t < S0; ++t) {    // warmup, discard outputs
            float xv = xs[padi(t)];
            float f = b0 * xv + b1 * xm1 + b2 * xm2 + b3 * xm3 + b4 * xm4 + b5 * xm5;
            float o = f - a1 * y1 - a2 * y2 - a3 * y3 - a4 * y4 - a5 * y5;
            y5 = y4; y4 = y3; y3 = y2; y2 = y1; y1 = o;
            xm5 = xm4; xm4 = xm3; xm3 = xm2; xm2 = xm1; xm1 = xv;
        }
        #pragma unroll 8
        for (int t = S0; t < S0 + CHUNK; ++t) {
            float xv = xs[padi(t)];
            float f = b0 * xv + b1 * xm1 + b2 * xm2 + b3 * xm3 + b4 * xm4 + b5 * xm5;
            float o = f - a1 * y1 - a2 * y2 - a3 * y3 - a4 * y4 - a5 * y5;
            y5 = y4; y4 = y3; y3 = y2; y2 = y1; y1 = o;
            xm5 = xm4; xm4 = xm3; xm3 = xm2; xm2 = xm1; xm1 = xv;
            ys[padi(t - HEAD)] = o;
        }
    }

    __syncthreads();

    // ---- Phase 3: coalesced store of y span ----
    #pragma unroll
    for (int it = 0; it < SPAN / 4 / BLOCK; ++it) {       // 8 iters
        int S = 4 * (j + it * BLOCK);
        int p = padi(S);
        float4 v;
        v.x = ys[p]; v.y = ys[p + 1]; v.z = ys[p + 2]; v.w = ys[p + 3];
        *(float4*)(yr + base + S) = v;
    }
}

extern "C" void kernel_launch(void* const* d_in, const int* in_sizes, int n_in,
                              void* d_out, int out_size, void* d_ws, size_t ws_size,
                              hipStream_t stream) {
    const float* x   = (const float*)d_in[0];
    const float* bco = (const float*)d_in[1];
    const float* aco = (const float*)d_in[2];
    float* y = (float*)d_out;

    const int grid = B_ROWS * BPR;   // 1024 blocks
    bessel_tile_kernel<<<grid, BLOCK, 0, stream>>>(x, bco, aco, y);
}

// Round 3
// 93.000 us; speedup vs baseline: 1.0837x; 1.0529x over previous
//
#include <hip/hip_runtime.h>

// Bessel order-5 IIR, B=64 x T=131072, f32.
// R2: single-phase LDS tile, direct register->global stores.
//  - WARM=32 (max |z-pole| = 0.601 -> 0.601^32 ~ 8e-8 truncation, far below thr)
//  - no ys staging: each thread's 32 outputs cover 2 full 64B lines -> L2 merges
//  - LDS 34 KB -> 4 blocks/CU; grid 1024 = full co-residency, single barrier
// Traffic floor: 33.5 MB read + 33.5 MB write ~ 11 us at 6.3 TB/s.

constexpr int T_LEN  = 131072;
constexpr int B_ROWS = 64;
constexpr int CHUNK  = 32;             // outputs per thread
constexpr int WARM   = 32;             // zero-state warmup samples
constexpr int HEAD   = 64;             // staged samples before span (warm+history)
constexpr int BLOCK  = 256;
constexpr int SPAN   = BLOCK * CHUNK;  // 8192 samples per block
constexpr int BPR    = T_LEN / SPAN;   // 16 blocks per row
constexpr int XTOT   = HEAD + SPAN;    // 8256 staged samples
constexpr int XPAD   = XTOT + XTOT / 32;  // 8514 floats = 34.1 KB

__device__ __forceinline__ int padi(int s) { return s + (s >> 5); }

__global__ __launch_bounds__(BLOCK, 4) void bessel_tile_kernel(
    const float* __restrict__ x,
    const float* __restrict__ bco,
    const float* __restrict__ aco,
    float* __restrict__ y)
{
    __shared__ float xs[XPAD];

    const int b    = blockIdx.x;
    const int row  = b / BPR;
    const int tile = b % BPR;
    const int base = tile * SPAN;
    const int j    = threadIdx.x;

    const float* __restrict__ xr  = x + (size_t)row * T_LEN;
    float* __restrict__       yrp = y + (size_t)row * T_LEN + base;

    // ---- Phase 1: stage x[base-HEAD .. base+SPAN) into padded LDS ----
    if (tile == 0) {
        if (j < HEAD) xs[padi(j)] = 0.0f;          // x[-64..0) == 0
        #pragma unroll
        for (int it = 0; it < SPAN / 4 / BLOCK; ++it) {   // 8 iters
            int k = j + it * BLOCK;
            float4 v = *(const float4*)(xr + base + 4 * k);
            int p = padi(HEAD + 4 * k);            // 4-aligned => contiguous
            xs[p] = v.x; xs[p + 1] = v.y; xs[p + 2] = v.z; xs[p + 3] = v.w;
        }
    } else {
        for (int k = j; k < XTOT / 4; k += BLOCK) {       // 2064 -> 9 iters
            float4 v = *(const float4*)(xr + base - HEAD + 4 * k);
            int p = padi(4 * k);
            xs[p] = v.x; xs[p + 1] = v.y; xs[p + 2] = v.z; xs[p + 3] = v.w;
        }
    }

    // normalized coefficients (uniform scalar loads)
    const float inv = 1.0f / aco[0];
    const float b0 = bco[0] * inv, b1 = bco[1] * inv, b2 = bco[2] * inv,
                b3 = bco[3] * inv, b4 = bco[4] * inv, b5 = bco[5] * inv;
    const float a1 = aco[1] * inv, a2 = aco[2] * inv, a3 = aco[3] * inv,
                a4 = aco[4] * inv, a5 = aco[5] * inv;

    __syncthreads();

    // ---- Phase 2: per-thread IIR, outputs straight to global ----
    const int S0 = HEAD + j * CHUNK;     // first owned sample (LDS index)
    int t = S0 - WARM;                   // >= 32 always

    float y1 = 0.f, y2 = 0.f, y3 = 0.f, y4 = 0.f, y5 = 0.f;
    float xm1 = xs[padi(t - 1)], xm2 = xs[padi(t - 2)], xm3 = xs[padi(t - 3)],
          xm4 = xs[padi(t - 4)], xm5 = xs[padi(t - 5)];

    #pragma unroll
    for (int i = 0; i < WARM; ++i, ++t) {        // warmup, discard outputs
        float xv = xs[padi(t)];
        float f = b0 * xv + b1 * xm1 + b2 * xm2 + b3 * xm3 + b4 * xm4 + b5 * xm5;
        float o = f - a1 * y1 - a2 * y2 - a3 * y3 - a4 * y4 - a5 * y5;
        y5 = y4; y4 = y3; y3 = y2; y2 = y1; y1 = o;
        xm5 = xm4; xm4 = xm3; xm3 = xm2; xm2 = xm1; xm1 = xv;
    }

    float* outp = yrp + j * CHUNK;
    #pragma unroll
    for (int g = 0; g < CHUNK / 4; ++g) {        // 8 groups of 4 samples
        float4 ov;
        #pragma unroll
        for (int i = 0; i < 4; ++i, ++t) {
            float xv = xs[padi(t)];
            float f = b0 * xv + b1 * xm1 + b2 * xm2 + b3 * xm3 + b4 * xm4 + b5 * xm5;
            float o = f - a1 * y1 - a2 * y2 - a3 * y3 - a4 * y4 - a5 * y5;
            y5 = y4; y4 = y3; y3 = y2; y2 = y1; y1 = o;
            xm5 = xm4; xm4 = xm3; xm3 = xm2; xm2 = xm1; xm1 = xv;
            (&ov.x)[i] = o;
        }
        *(float4*)(outp + 4 * g) = ov;           // 2 full lines/thread total
    }
}

extern "C" void kernel_launch(void* const* d_in, const int* in_sizes, int n_in,
                              void* d_out, int out_size, void* d_ws, size_t ws_size,
                              hipStream_t stream) {
    const float* x   = (const float*)d_in[0];
    const float* bco = (const float*)d_in[1];
    const float* aco = (const float*)d_in[2];
    float* y = (float*)d_out;

    const int grid = B_ROWS * BPR;   // 1024 blocks = 4/CU x 256 CU
    bessel_tile_kernel<<<grid, BLOCK, 0, stream>>>(x, bco, aco, y);
}

// Round 4
// 91.872 us; speedup vs baseline: 1.0970x; 1.0123x over previous
//
#include <hip/hip_runtime.h>

// Bessel order-5 IIR, B=64 x T=131072, f32.
// R3: reassociated recurrence -> 1-FMA dependent chain per step.
//  - FIR taps (f0..f3) per 4-group hoisted: independent of y-state, pipeline freely.
//  - recurrence written newest-dependency-LAST: ((((f - a5*y5) - a4*y4) - a3*y3)
//    - a2*y2) - a1*y1, so the serial chain is 1 FMA/step (~4 cyc) not 5 (~20 cyc).
//  - otherwise R2 structure: LDS tile 34 KB (4 blocks/CU, grid 1024 = fully
//    co-resident), WARM=32 (|pole|max 0.601 -> 0.601^32 ~ 8e-8), direct float4
//    register->global stores (2 full lines/thread).
// Floor: 33.5 MB read + 33.5 MB write ~ 10.6 us at 6.3 TB/s.

constexpr int T_LEN  = 131072;
constexpr int B_ROWS = 64;
constexpr int CHUNK  = 32;             // outputs per thread
constexpr int WARM   = 32;             // zero-state warmup samples
constexpr int HEAD   = 64;             // staged samples before span
constexpr int BLOCK  = 256;
constexpr int SPAN   = BLOCK * CHUNK;  // 8192 samples per block
constexpr int BPR    = T_LEN / SPAN;   // 16 blocks per row
constexpr int XTOT   = HEAD + SPAN;    // 8256 staged samples
constexpr int XPAD   = XTOT + XTOT / 32;  // 8514 floats = 34.1 KB

__device__ __forceinline__ int padi(int s) { return s + (s >> 5); }

__global__ __launch_bounds__(BLOCK, 4) void bessel_tile_kernel(
    const float* __restrict__ x,
    const float* __restrict__ bco,
    const float* __restrict__ aco,
    float* __restrict__ y)
{
    __shared__ float xs[XPAD];

    const int b    = blockIdx.x;
    const int row  = b / BPR;
    const int tile = b % BPR;
    const int base = tile * SPAN;
    const int j    = threadIdx.x;

    const float* __restrict__ xr  = x + (size_t)row * T_LEN;
    float* __restrict__       yrp = y + (size_t)row * T_LEN + base;

    // ---- Phase 1: stage x[base-HEAD .. base+SPAN) into padded LDS ----
    if (tile == 0) {
        if (j < HEAD) xs[padi(j)] = 0.0f;          // x[-64..0) == 0
        #pragma unroll
        for (int it = 0; it < SPAN / 4 / BLOCK; ++it) {   // 8 iters
            int k = j + it * BLOCK;
            float4 v = *(const float4*)(xr + base + 4 * k);
            int p = padi(HEAD + 4 * k);            // 4-aligned => contiguous
            xs[p] = v.x; xs[p + 1] = v.y; xs[p + 2] = v.z; xs[p + 3] = v.w;
        }
    } else {
        for (int k = j; k < XTOT / 4; k += BLOCK) {       // 2064 -> 9 iters
            float4 v = *(const float4*)(xr + base - HEAD + 4 * k);
            int p = padi(4 * k);
            xs[p] = v.x; xs[p + 1] = v.y; xs[p + 2] = v.z; xs[p + 3] = v.w;
        }
    }

    // normalized coefficients (uniform scalar loads)
    const float inv = 1.0f / aco[0];
    const float b0 = bco[0] * inv, b1 = bco[1] * inv, b2 = bco[2] * inv,
                b3 = bco[3] * inv, b4 = bco[4] * inv, b5 = bco[5] * inv;
    const float a1 = aco[1] * inv, a2 = aco[2] * inv, a3 = aco[3] * inv,
                a4 = aco[4] * inv, a5 = aco[5] * inv;

    __syncthreads();

    // ---- Phase 2: per-thread IIR, 4 samples per group ----
    const int S0 = HEAD + j * CHUNK;     // first owned sample (LDS index)
    int t = S0 - WARM;                   // >= 32 always

    float y1 = 0.f, y2 = 0.f, y3 = 0.f, y4 = 0.f, y5 = 0.f;
    float xm1 = xs[padi(t - 1)], xm2 = xs[padi(t - 2)], xm3 = xs[padi(t - 3)],
          xm4 = xs[padi(t - 4)], xm5 = xs[padi(t - 5)];

    // one 4-sample group: FIR hoisted, recurrence chain = 1 FMA/step
    auto group4 = [&](float& o0, float& o1, float& o2, float& o3) {
        float x0 = xs[padi(t)], x1 = xs[padi(t + 1)],
              x2 = xs[padi(t + 2)], x3 = xs[padi(t + 3)];
        float f0 = b0 * x0 + b1 * xm1 + b2 * xm2 + b3 * xm3 + b4 * xm4 + b5 * xm5;
        float f1 = b0 * x1 + b1 * x0 + b2 * xm1 + b3 * xm2 + b4 * xm3 + b5 * xm4;
        float f2 = b0 * x2 + b1 * x1 + b2 * x0 + b3 * xm1 + b4 * xm2 + b5 * xm3;
        float f3 = b0 * x3 + b1 * x2 + b2 * x1 + b3 * x0 + b4 * xm1 + b5 * xm2;
        o0 = ((((f0 - a5 * y5) - a4 * y4) - a3 * y3) - a2 * y2) - a1 * y1;
        o1 = ((((f1 - a5 * y4) - a4 * y3) - a3 * y2) - a2 * y1) - a1 * o0;
        o2 = ((((f2 - a5 * y3) - a4 * y2) - a3 * y1) - a2 * o0) - a1 * o1;
        o3 = ((((f3 - a5 * y2) - a4 * y1) - a3 * o0) - a2 * o1) - a1 * o2;
        y5 = y1; y4 = o0; y3 = o1; y2 = o2; y1 = o3;
        xm5 = xm1; xm4 = x0; xm3 = x1; xm2 = x2; xm1 = x3;
        t += 4;
    };

    #pragma unroll
    for (int g = 0; g < WARM / 4; ++g) {          // warmup, discard
        float d0, d1, d2, d3;
        group4(d0, d1, d2, d3);
    }

    float* outp = yrp + j * CHUNK;
    #pragma unroll
    for (int g = 0; g < CHUNK / 4; ++g) {         // 8 output groups
        float4 ov;
        group4(ov.x, ov.y, ov.z, ov.w);
        *(float4*)(outp + 4 * g) = ov;            // 2 full 64B lines/thread
    }
}

extern "C" void kernel_launch(void* const* d_in, const int* in_sizes, int n_in,
                              void* d_out, int out_size, void* d_ws, size_t ws_size,
                              hipStream_t stream) {
    const float* x   = (const float*)d_in[0];
    const float* bco = (const float*)d_in[1];
    const float* aco = (const float*)d_in[2];
    float* y = (float*)d_out;

    const int grid = B_ROWS * BPR;   // 1024 blocks = 4/CU x 256 CU
    bessel_tile_kernel<<<grid, BLOCK, 0, stream>>>(x, bco, aco, y);
}